// Round 19
// baseline (451.327 us; speedup 1.0000x reference)
//
#include <hip/hip_runtime.h>

#define NEGS   0.2f
#define LN_EPS 1e-5f
#define BSH    7          // 128 nodes per bucket
#define BN     128
#define TILE   4096       // edges per tile block
#define LOG2E  1.44269504f

typedef const float* __restrict__ fp;
typedef _Float16 v2h __attribute__((ext_vector_type(2)));
typedef _Float16 v8h __attribute__((ext_vector_type(8)));
typedef float    v4f __attribute__((ext_vector_type(4)));

__device__ __forceinline__ v2h u2h(unsigned u){ union{unsigned u; v2h h;} c; c.u = u; return c.h; }
__device__ __forceinline__ unsigned h2u(v2h h){ union{v2h h; unsigned u;} c; c.h = h; return c.u; }

// pure-VALU 8-lane sum via compiler-managed DPP (hazard nops inserted by backend)
template<int CTRL>
__device__ __forceinline__ float dppadd(float x){
  int y = __builtin_amdgcn_update_dpp(0, __float_as_int(x), CTRL, 0xF, 0xF, true);
  return x + __int_as_float(y);
}
__device__ __forceinline__ float hsum8(float s){
  s = dppadd<0xB1>(s);    // xor 1
  s = dppadd<0x4E>(s);    // xor 2
  s = dppadd<0x141>(s);   // row_half_mirror: cross-quad within 8-lane group
  return s;
}
__device__ __forceinline__ float edge_w(v2h v, v2h xrv, v2h att2, float negm8){
  v2h t = v + xrv;
  t = __builtin_elementwise_max(t, t * (_Float16)NEGS);
  float s = hsum8(__builtin_amdgcn_fdot2(t, att2, negm8, false));
  return __builtin_amdgcn_exp2f(s);
}

// ===== fused: input transform (+h16) | edge histograms | ctr zero | weight prep =====
__global__ __launch_bounds__(256) void f_in_hist(fp x, fp w, fp b, float* __restrict__ h,
                                                 unsigned* __restrict__ h16,
                                                 const int* __restrict__ dstA, int* __restrict__ counts,
                                                 int* __restrict__ ctr,
                                                 fp w_l, fp w_r, _Float16* __restrict__ wf,
                                                 int N, int E, int K, int ntiles, int NB_IN){
  __shared__ __align__(16) float sm[1700];
  int bid = blockIdx.x, tid = threadIdx.x;
  if (bid < NB_IN){
    float* ws = sm;            // 1536
    float* bs = sm + 1536;     // 64
    float* xs = sm + 1600;     // 4*24
    for (int i = tid; i < 1536; i += 256) ws[i] = w[i];
    if (tid < 64) bs[tid] = b[tid];
    int r = tid >> 6, c = tid & 63;
    int row = bid*4 + r;
    if (c < 24 && row < N) xs[r*24 + c] = x[row*24 + c];
    __syncthreads();
    float acc = bs[c];
    #pragma unroll
    for (int k = 0; k < 24; ++k) acc = fmaf(xs[r*24 + k], ws[k*64 + c], acc);
    float y = fmaxf(acc, 0.f);
    float y1 = __shfl_down(y, 1);
    if (row < N){
      h[(size_t)row*64 + c] = y;
      if (!(c & 1)){
        v2h p; p.x = (_Float16)y; p.y = (_Float16)y1;
        h16[(size_t)row*32 + (c >> 1)] = h2u(p);
      }
    }
  } else if (bid < NB_IN + ntiles){
    int* hist = (int*)sm;
    int t = bid - NB_IN;
    for (int i = tid; i < K; i += 256) hist[i] = 0;
    __syncthreads();
    int e0 = t*TILE, e1 = min(e0 + TILE, E);
    for (int e = e0 + tid; e < e1; e += 256)
      atomicAdd(&hist[dstA[e] >> BSH], 1);
    __syncthreads();
    for (int i = tid; i < K; i += 256) counts[i*ntiles + t] = hist[i];
  } else if (bid == NB_IN + ntiles){
    if (tid == 0) ctr[0] = 0;
  } else {
    // weight prep: swizzle w_l/w_r into MFMA B-fragment layout (f16)
    int lm = bid - NB_IN - ntiles - 1;      // 0..5 : layer*2 + mat
    const float* src = ((lm & 1) ? w_r : w_l) + (lm >> 1)*4096;
    _Float16* dst = wf + lm*4096;
    for (int d = tid; d < 4096; d += 256){
      int j = d & 7, l = (d >> 3) & 63, kc = (d >> 9) & 1, nt = d >> 10;
      int k = kc*32 + (l >> 4)*8 + j;
      int n = nt*16 + (l & 15);
      dst[d] = (_Float16)src[k*64 + n];
    }
  }
}

// ===== fused scan: per-bucket tile scan + last-block bucket scan =====
__global__ __launch_bounds__(512) void s_scan(int* __restrict__ counts, int* __restrict__ btotal,
                                              int* __restrict__ bbase, int* __restrict__ ctr,
                                              int K, int E, int ntiles){
  __shared__ int s[512];
  __shared__ int isLast;
  int b = blockIdx.x, tid = threadIdx.x;
  int v = (tid < ntiles) ? counts[b*ntiles + tid] : 0;
  s[tid] = v;
  __syncthreads();
  for (int off = 1; off < 512; off <<= 1){
    int t = (tid >= off) ? s[tid - off] : 0;
    __syncthreads();
    s[tid] += t;
    __syncthreads();
  }
  if (tid < ntiles) counts[b*ntiles + tid] = s[tid] - v;
  if (tid == 511) btotal[b] = s[511];
  __threadfence();
  __syncthreads();
  if (tid == 0){ int old = atomicAdd(ctr, 1); isLast = (old == (int)gridDim.x - 1) ? 1 : 0; }
  __syncthreads();
  if (!isLast) return;
  __threadfence();
  int v2 = (tid < K) ? btotal[tid] : 0;
  s[tid] = v2;
  __syncthreads();
  for (int off = 1; off < 512; off <<= 1){
    int t = (tid >= off) ? s[tid - off] : 0;
    __syncthreads();
    s[tid] += t;
    __syncthreads();
  }
  if (tid < K) bbase[tid] = s[tid] - v2;
  if (tid == 0) bbase[K] = E;
}

__global__ __launch_bounds__(256) void t_scatter(const int* __restrict__ srcA, const int* __restrict__ dstA,
                                                 const int* __restrict__ counts, const int* __restrict__ bbase,
                                                 unsigned* __restrict__ packed, int E, int K, int ntiles){
  __shared__ int gb[512];
  __shared__ int cur[512];
  int t = blockIdx.x, tid = threadIdx.x;
  for (int i = tid; i < K; i += 256){
    gb[i] = bbase[i] + counts[i*ntiles + t];
    cur[i] = 0;
  }
  __syncthreads();
  int e0 = t*TILE, e1 = min(e0 + TILE, E);
  for (int e = e0 + tid; e < e1; e += 256){
    int d = dstA[e], sv = srcA[e];
    int b = d >> BSH;
    int p = atomicAdd(&cur[b], 1);
    packed[gb[b] + p] = ((unsigned)(d & (BN-1)) << 25) | (unsigned)sv;
  }
}

__global__ __launch_bounds__(256) void k_fine(const unsigned* __restrict__ packed, const int* __restrict__ bbase,
                                              int* __restrict__ row_ptr, int* __restrict__ col, int N, int K){
  __shared__ int hist[BN];
  __shared__ int excl[BN];
  int b = blockIdx.x, tid = threadIdx.x;
  int node0 = b << BSH;
  int e_base = bbase[b], e_end = bbase[b+1];
  if (tid < BN) hist[tid] = 0;
  __syncthreads();
  for (int e = e_base + tid; e < e_end; e += 256)
    atomicAdd(&hist[packed[e] >> 25], 1);
  __syncthreads();
  int v = (tid < BN) ? hist[tid] : 0;
  if (tid < BN) excl[tid] = v;
  __syncthreads();
  for (int off = 1; off < BN; off <<= 1){
    int t2 = 0;
    if (tid < BN && tid >= off) t2 = excl[tid - off];
    __syncthreads();
    if (tid < BN) excl[tid] += t2;
    __syncthreads();
  }
  int nn = min(BN, N - node0);
  if (tid < nn) row_ptr[node0 + tid] = e_base + excl[tid] - v;
  if (b == K-1 && tid == 0) row_ptr[N] = e_end;
  if (tid < BN) hist[tid] = excl[tid] - v;
  __syncthreads();
  for (int e = e_base + tid; e < e_end; e += 256){
    unsigned u = packed[e];
    int dl = u >> 25;
    int p = atomicAdd(&hist[dl], 1);
    col[e_base + p] = (int)(u & 0x1FFFFFFu);
  }
}

// ---------------- per-layer transforms via MFMA: xl16/xr16 = f16(h @ w + b) ----------------
__global__ __launch_bounds__(256) void k_xfm(const unsigned* __restrict__ h16,
                                             const _Float16* __restrict__ wf,   // layer base
                                             fp blg, fp brg,
                                             unsigned* __restrict__ xl16, unsigned* __restrict__ xr16, int N){
  int tid = threadIdx.x, wave = tid >> 6, lane = tid & 63;
  int quad = lane >> 4, ln = lane & 15;
  int m0 = blockIdx.x*64 + wave*16;
  if (m0 >= N) return;
  int m = m0 + ln;
  bool mv = m < N;
  v8h a0 = {}, a1 = {};
  if (mv){
    a0 = *(const v8h*)&h16[(size_t)m*32 + quad*4];
    a1 = *(const v8h*)&h16[(size_t)m*32 + 16 + quad*4];
  }
  #pragma unroll
  for (int mat = 0; mat < 2; ++mat){
    const _Float16* wb = wf + mat*4096;
    fp bias = mat ? brg : blg;
    unsigned* dst = mat ? xr16 : xl16;
    #pragma unroll
    for (int nt = 0; nt < 4; ++nt){
      v8h b0 = *(const v8h*)&wb[nt*1024 + lane*8];
      v8h b1 = *(const v8h*)&wb[nt*1024 + 512 + lane*8];
      float bv = bias[nt*16 + ln];
      v4f acc = {bv, bv, bv, bv};
      acc = __builtin_amdgcn_mfma_f32_16x16x32_f16(a0, b0, acc, 0, 0, 0);
      acc = __builtin_amdgcn_mfma_f32_16x16x32_f16(a1, b1, acc, 0, 0, 0);
      #pragma unroll
      for (int r = 0; r < 4; ++r){
        float partner = __shfl_xor(acc[r], 1);
        int node = m0 + quad*4 + r;
        if (!(lane & 1) && node < N){
          v2h p; p.x = (_Float16)acc[r]; p.y = (_Float16)partner;
          dst[(size_t)node*32 + nt*8 + (ln >> 1)] = h2u(p);
        }
      }
    }
  }
}

// ---------------- fused GATv2 aggregation + residual + LayerNorm (+relu) ----------------
// xl/xr packed f16 (2 features/lane, 32 lanes/row). Wave processes 2 edges at once;
// 16-edge unroll with dwordx4 col loads (alignment prologue keeps e%4==0).
__global__ __launch_bounds__(256) void k_gat(const unsigned* __restrict__ xl16, const unsigned* __restrict__ xr16,
                                             float* __restrict__ h, unsigned* __restrict__ h16,
                                             const int* __restrict__ row_ptr, const int* __restrict__ col,
                                             fp att, fp bg, fp lng, fp lnb, int N, int do_relu){
  int lane = threadIdx.x & 63;
  int node = blockIdx.x*4 + (threadIdx.x >> 6);
  if (node >= N) return;
  int l = lane & 31;
  bool lower = lane < 32;
  int off = lower ? 0 : 1;
  v2h att2; att2.x = (_Float16)(att[2*l] * LOG2E); att2.y = (_Float16)(att[2*l+1] * LOG2E);
  v2h xrv = u2h(xr16[(size_t)node*32 + l]);
  v2h xlv = u2h(xl16[(size_t)node*32 + l]);
  v2h ts = xlv + xrv;
  ts = __builtin_elementwise_max(ts, ts * (_Float16)NEGS);
  const float m = hsum8(__builtin_amdgcn_fdot2(ts, att2, 0.f, false));
  const float negm8 = m * -0.125f;
  float den0 = lower ? 1.f : 0.f, den1 = 0.f, den2 = 0.f, den3 = 0.f;
  float a0x = lower ? (float)xlv.x : 0.f, a0y = lower ? (float)xlv.y : 0.f;
  float a1x = 0.f, a1y = 0.f, a2x = 0.f, a2y = 0.f, a3x = 0.f, a3y = 0.f;
  int e = row_ptr[node], e1 = row_ptr[node+1];
  // align e to 4 (singles; upper half zeroed to avoid double-count)
  while ((e & 3) && e < e1){
    int j0 = col[e];
    v2h v0 = u2h(xl16[(size_t)j0*32 + l]);
    float w0 = edge_w(v0, xrv, att2, negm8);
    if (!lower) w0 = 0.f;
    den0 += w0; a0x = fmaf(w0, (float)v0.x, a0x); a0y = fmaf(w0, (float)v0.y, a0y);
    ++e;
  }
  for (; e + 16 <= e1; e += 16){
    int4 c0 = *(const int4*)&col[e];
    int4 c1 = *(const int4*)&col[e+4];
    int4 c2 = *(const int4*)&col[e+8];
    int4 c3 = *(const int4*)&col[e+12];
    int j0 = lower ? c0.x : c0.y;
    int j1 = lower ? c0.z : c0.w;
    int j2 = lower ? c1.x : c1.y;
    int j3 = lower ? c1.z : c1.w;
    int j4 = lower ? c2.x : c2.y;
    int j5 = lower ? c2.z : c2.w;
    int j6 = lower ? c3.x : c3.y;
    int j7 = lower ? c3.z : c3.w;
    v2h v0 = u2h(xl16[(size_t)j0*32 + l]);
    v2h v1 = u2h(xl16[(size_t)j1*32 + l]);
    v2h v2 = u2h(xl16[(size_t)j2*32 + l]);
    v2h v3 = u2h(xl16[(size_t)j3*32 + l]);
    v2h v4 = u2h(xl16[(size_t)j4*32 + l]);
    v2h v5 = u2h(xl16[(size_t)j5*32 + l]);
    v2h v6 = u2h(xl16[(size_t)j6*32 + l]);
    v2h v7 = u2h(xl16[(size_t)j7*32 + l]);
    float w0 = edge_w(v0, xrv, att2, negm8);
    float w1 = edge_w(v1, xrv, att2, negm8);
    float w2 = edge_w(v2, xrv, att2, negm8);
    float w3 = edge_w(v3, xrv, att2, negm8);
    float w4 = edge_w(v4, xrv, att2, negm8);
    float w5 = edge_w(v5, xrv, att2, negm8);
    float w6 = edge_w(v6, xrv, att2, negm8);
    float w7 = edge_w(v7, xrv, att2, negm8);
    den0 += w0; a0x = fmaf(w0, (float)v0.x, a0x); a0y = fmaf(w0, (float)v0.y, a0y);
    den1 += w1; a1x = fmaf(w1, (float)v1.x, a1x); a1y = fmaf(w1, (float)v1.y, a1y);
    den2 += w2; a2x = fmaf(w2, (float)v2.x, a2x); a2y = fmaf(w2, (float)v2.y, a2y);
    den3 += w3; a3x = fmaf(w3, (float)v3.x, a3x); a3y = fmaf(w3, (float)v3.y, a3y);
    den0 += w4; a0x = fmaf(w4, (float)v4.x, a0x); a0y = fmaf(w4, (float)v4.y, a0y);
    den1 += w5; a1x = fmaf(w5, (float)v5.x, a1x); a1y = fmaf(w5, (float)v5.y, a1y);
    den2 += w6; a2x = fmaf(w6, (float)v6.x, a2x); a2y = fmaf(w6, (float)v6.y, a2y);
    den3 += w7; a3x = fmaf(w7, (float)v7.x, a3x); a3y = fmaf(w7, (float)v7.y, a3y);
  }
  for (; e + 8 <= e1; e += 8){
    int4 c0 = *(const int4*)&col[e];
    int4 c1 = *(const int4*)&col[e+4];
    int j0 = lower ? c0.x : c0.y;
    int j1 = lower ? c0.z : c0.w;
    int j2 = lower ? c1.x : c1.y;
    int j3 = lower ? c1.z : c1.w;
    v2h v0 = u2h(xl16[(size_t)j0*32 + l]);
    v2h v1 = u2h(xl16[(size_t)j1*32 + l]);
    v2h v2 = u2h(xl16[(size_t)j2*32 + l]);
    v2h v3 = u2h(xl16[(size_t)j3*32 + l]);
    float w0 = edge_w(v0, xrv, att2, negm8);
    float w1 = edge_w(v1, xrv, att2, negm8);
    float w2 = edge_w(v2, xrv, att2, negm8);
    float w3 = edge_w(v3, xrv, att2, negm8);
    den0 += w0; a0x = fmaf(w0, (float)v0.x, a0x); a0y = fmaf(w0, (float)v0.y, a0y);
    den1 += w1; a1x = fmaf(w1, (float)v1.x, a1x); a1y = fmaf(w1, (float)v1.y, a1y);
    den2 += w2; a2x = fmaf(w2, (float)v2.x, a2x); a2y = fmaf(w2, (float)v2.y, a2y);
    den3 += w3; a3x = fmaf(w3, (float)v3.x, a3x); a3y = fmaf(w3, (float)v3.y, a3y);
  }
  for (; e + 2 <= e1; e += 2){
    int j0 = col[e+off];
    v2h v0 = u2h(xl16[(size_t)j0*32 + l]);
    float w0 = edge_w(v0, xrv, att2, negm8);
    den0 += w0; a0x = fmaf(w0, (float)v0.x, a0x); a0y = fmaf(w0, (float)v0.y, a0y);
  }
  if (e < e1){
    int j0 = col[e];
    v2h v0 = u2h(xl16[(size_t)j0*32 + l]);
    float w0 = edge_w(v0, xrv, att2, negm8);
    if (!lower) w0 = 0.f;
    den0 += w0; a0x = fmaf(w0, (float)v0.x, a0x); a0y = fmaf(w0, (float)v0.y, a0y);
  }
  float den = (den0 + den1) + (den2 + den3);
  float ax = (a0x + a1x) + (a2x + a3x);
  float ay = (a0y + a1y) + (a2y + a3y);
  den += __shfl_xor(den, 32);
  ax  += __shfl_xor(ax, 32);
  ay  += __shfl_xor(ay, 32);
  float inv = 1.f / den;
  float2 bg2 = *(const float2*)&bg[2*l];
  float2 h2  = *(const float2*)&h[(size_t)node*64 + 2*l];
  float ox = ax*inv + bg2.x + h2.x;
  float oy = ay*inv + bg2.y + h2.y;
  float sl = ox + oy;
  #pragma unroll
  for (int o = 1; o < 32; o <<= 1) sl += __shfl_xor(sl, o);
  float mean = sl * (1.f/64.f);
  float dx = ox - mean, dy = oy - mean;
  float vsl = dx*dx + dy*dy;
  #pragma unroll
  for (int o = 1; o < 32; o <<= 1) vsl += __shfl_xor(vsl, o);
  float rs = rsqrtf(vsl * (1.f/64.f) + LN_EPS);
  float2 lg2 = *(const float2*)&lng[2*l];
  float2 lb2 = *(const float2*)&lnb[2*l];
  float yx = dx*rs*lg2.x + lb2.x;
  float yy = dy*rs*lg2.y + lb2.y;
  if (do_relu){ yx = fmaxf(yx, 0.f); yy = fmaxf(yy, 0.f); }
  if (lower){
    float2 y2; y2.x = yx; y2.y = yy;
    *(float2*)&h[(size_t)node*64 + 2*l] = y2;
    v2h p; p.x = (_Float16)yx; p.y = (_Float16)yy;
    h16[(size_t)node*32 + l] = h2u(p);
  }
}

// ---------------- gate MLP ----------------
__global__ __launch_bounds__(256) void k_gate(const float* __restrict__ h, fp w1, fp b1, fp w2, fp b2,
                                              float* __restrict__ gate, int N){
  __shared__ float w1s[2048];
  __shared__ float hrow[16][64];
  int tid = threadIdx.x;
  for (int i = tid*4; i < 2048; i += 1024) *(float4*)&w1s[i] = *(const float4*)&w1[i];
  int base = blockIdx.x*16;
  int nrows = min(16, N - base);
  int lim = nrows*64;
  for (int i = tid*4; i < lim; i += 1024)
    *(float4*)&hrow[0][i] = *(const float4*)&h[(size_t)base*64 + i];
  __syncthreads();
  int wave = tid >> 6, lane = tid & 63;
  int j = lane & 31, half = lane >> 5;
  float b1v = b1[j], w2v = w2[j], b2v = b2[0];
  int k0 = half*32;
  #pragma unroll
  for (int it = 0; it < 4; ++it){
    int r = wave*4 + it;
    int node = base + r;
    if (node >= N) break;
    float s = 0.f;
    #pragma unroll 8
    for (int k = k0; k < k0 + 32; ++k) s = fmaf(hrow[r][k], w1s[k*32 + j], s);
    s += __shfl_xor(s, 32);
    float hid = fmaxf(s + b1v, 0.f);
    float contrib = (half == 0) ? hid * w2v : 0.f;
    #pragma unroll
    for (int o = 1; o < 64; o <<= 1) contrib += __shfl_xor(contrib, o);
    if (lane == 0) gate[node] = contrib + b2v;
  }
}

// ---------------- per-graph gate max + zero pool accumulators ----------------
__global__ __launch_bounds__(256) void k_gmax(const float* __restrict__ gate, const int* __restrict__ batch,
                                              float* __restrict__ gmax, float* __restrict__ gsum,
                                              float* __restrict__ embsum, int N){
  int g = blockIdx.x, tid = threadIdx.x;
  if (tid < 64) embsum[g*64 + tid] = 0.f;
  if (tid == 64) gsum[g] = 0.f;
  int lo = 0, hi = N;
  while (lo < hi){ int mid = (lo + hi) >> 1; if (batch[mid] < g) lo = mid + 1; else hi = mid; }
  int start = lo;
  hi = N;
  while (lo < hi){ int mid = (lo + hi) >> 1; if (batch[mid] < g + 1) lo = mid + 1; else hi = mid; }
  int end = lo;
  float m = -3.4e38f;
  for (int i = start + tid; i < end; i += 256) m = fmaxf(m, gate[i]);
  #pragma unroll
  for (int o = 1; o < 64; o <<= 1) m = fmaxf(m, __shfl_xor(m, o));
  __shared__ float ws[4];
  if ((tid & 63) == 0) ws[tid >> 6] = m;
  __syncthreads();
  if (tid == 0) gmax[g] = fmaxf(fmaxf(ws[0], ws[1]), fmaxf(ws[2], ws[3]));
}

// ---------------- pooling accumulate (reads packed-f16 h16) ----------------
__global__ __launch_bounds__(256) void k_emb(const unsigned* __restrict__ h16, const float* __restrict__ gate,
                                             const int* __restrict__ batch, const float* __restrict__ gmax,
                                             float* __restrict__ gsum, float* __restrict__ embsum, int N){
  int lane = threadIdx.x & 63;
  int half = lane & 1, li = lane >> 1;
  int wv = blockIdx.x*4 + (threadIdx.x >> 6);
  int s = wv*64;
  if (s >= N) return;
  int e = min(s + 64, N);
  int cur = batch[s];
  float gm = gmax[cur];
  float acc = 0.f, asum = 0.f;
  for (int i = s; i < e; ++i){
    int g = batch[i];
    if (g != cur){
      atomicAdd(&embsum[cur*64 + lane], acc);
      if (lane == 0) atomicAdd(&gsum[cur], asum);
      acc = 0.f; asum = 0.f; cur = g; gm = gmax[g];
    }
    float a = __expf(gate[i] - gm);
    v2h p = u2h(h16[(size_t)i*32 + li]);
    float hv = half ? (float)p.y : (float)p.x;
    acc = fmaf(a, hv, acc);
    asum += a;
  }
  atomicAdd(&embsum[cur*64 + lane], acc);
  if (lane == 0) atomicAdd(&gsum[cur], asum);
}

// ---------------- final GEMM ----------------
__global__ __launch_bounds__(64) void k_out(const float* __restrict__ embsum, const float* __restrict__ gsum,
                                            fp w_out, fp b_out, float* __restrict__ out, int G){
  int g = blockIdx.x, lane = threadIdx.x;
  __shared__ float emb[64];
  float gs = gsum[g];
  float inv = (gs > 0.f) ? 1.f/gs : 1.f;
  emb[lane] = embsum[g*64 + lane] * inv;
  __syncthreads();
  float o2 = b_out[lane];
  #pragma unroll 8
  for (int d = 0; d < 64; ++d) o2 = fmaf(emb[d], w_out[d*64 + lane], o2);
  out[g*64 + lane] = fmaxf(o2, 0.f);
}

extern "C" void kernel_launch(void* const* d_in, const int* in_sizes, int n_in,
                              void* d_out, int out_size, void* d_ws, size_t ws_size,
                              hipStream_t stream) {
  const int N = in_sizes[0] / 24;
  const int E = in_sizes[1] / 2;
  const int G = out_size / 64;
  const int K = (N + BN - 1) >> BSH;
  const int ntiles = (E + TILE - 1) / TILE;
  const int NB_IN = (N + 3) / 4;

  fp x      = (fp)d_in[0];
  const int* edge  = (const int*)d_in[1];
  const int* batch = (const int*)d_in[2];
  fp w_in   = (fp)d_in[3];
  fp b_in   = (fp)d_in[4];
  fp w_l    = (fp)d_in[5];
  fp b_l    = (fp)d_in[6];
  fp w_r    = (fp)d_in[7];
  fp b_r    = (fp)d_in[8];
  fp att    = (fp)d_in[9];
  fp b_gat  = (fp)d_in[10];
  fp ln_g   = (fp)d_in[11];
  fp ln_b   = (fp)d_in[12];
  fp w_g1   = (fp)d_in[13];
  fp b_g1   = (fp)d_in[14];
  fp w_g2   = (fp)d_in[15];
  fp b_g2   = (fp)d_in[16];
  fp w_out  = (fp)d_in[17];
  fp b_out  = (fp)d_in[18];
  float* out = (float*)d_out;

  char* wp = (char*)d_ws;
  auto alloc = [&](size_t bytes) -> char* {
    char* p = wp; wp += (bytes + 255) & ~(size_t)255; return p;
  };
  float*    h       = (float*)    alloc((size_t)N*64*sizeof(float));
  unsigned* h16     = (unsigned*) alloc((size_t)N*32*sizeof(unsigned));
  unsigned* xl16    = (unsigned*) alloc((size_t)N*32*sizeof(unsigned));
  unsigned* xr16    = (unsigned*) alloc((size_t)N*32*sizeof(unsigned));
  int*      col     = (int*)      alloc((size_t)E*sizeof(int));
  unsigned* packed  = (unsigned*) alloc((size_t)E*sizeof(unsigned));
  int*      counts  = (int*)      alloc((size_t)K*ntiles*sizeof(int));
  int*      btotal  = (int*)      alloc((size_t)K*sizeof(int));
  int*      bbase   = (int*)      alloc((size_t)(K+1)*sizeof(int));
  int*      row_ptr = (int*)      alloc((size_t)(N+1)*sizeof(int));
  float*    gate    = (float*)    alloc((size_t)N*sizeof(float));
  float*    gmax    = (float*)    alloc((size_t)G*sizeof(float));
  float*    gsum    = (float*)    alloc((size_t)(G + G*64)*sizeof(float));
  float*    embsum  = gsum + G;
  _Float16* wf      = (_Float16*) alloc((size_t)3*2*4096*sizeof(_Float16));
  int*      ctr     = (int*)      alloc(256);

  const int* srcA = edge;
  const int* dstA = edge + E;

  f_in_hist<<<NB_IN + ntiles + 7, 256, 0, stream>>>(x, w_in, b_in, h, h16, dstA, counts,
                                                    ctr, w_l, w_r, wf, N, E, K, ntiles, NB_IN);
  s_scan<<<K, 512, 0, stream>>>(counts, btotal, bbase, ctr, K, E, ntiles);
  t_scatter<<<ntiles, 256, 0, stream>>>(srcA, dstA, counts, bbase, packed, E, K, ntiles);
  k_fine<<<K, 256, 0, stream>>>(packed, bbase, row_ptr, col, N, K);

  for (int i = 0; i < 3; ++i){
    k_xfm<<<(N + 63)/64, 256, 0, stream>>>(h16, wf + i*8192, b_l + i*64, b_r + i*64,
                                           xl16, xr16, N);
    k_gat<<<(N + 3)/4, 256, 0, stream>>>(xl16, xr16, h, h16, row_ptr, col,
                                         att + i*64, b_gat + i*64, ln_g + i*64, ln_b + i*64,
                                         N, i < 2 ? 1 : 0);
  }
  k_gate<<<(N + 15)/16, 256, 0, stream>>>(h, w_g1, b_g1, w_g2, b_g2, gate, N);
  k_gmax<<<G, 256, 0, stream>>>(gate, batch, gmax, gsum, embsum, N);
  k_emb<<<(N + 255)/256, 256, 0, stream>>>(h16, gate, batch, gmax, gsum, embsum, N);
  k_out<<<G, 64, 0, stream>>>(embsum, gsum, w_out, b_out, out, G);
}

// Round 20
// 382.720 us; speedup vs baseline: 1.1793x; 1.1793x over previous
//
#include <hip/hip_runtime.h>

#define NEGS   0.2f
#define LN_EPS 1e-5f
#define BSH    7          // 128 nodes per bucket
#define BN     128
#define TILE   4096       // edges per tile block
#define LOG2E  1.44269504f

typedef const float* __restrict__ fp;
typedef _Float16 v2h __attribute__((ext_vector_type(2)));
typedef _Float16 v8h __attribute__((ext_vector_type(8)));
typedef float    v4f __attribute__((ext_vector_type(4)));

__device__ __forceinline__ v2h u2h(unsigned u){ union{unsigned u; v2h h;} c; c.u = u; return c.h; }
__device__ __forceinline__ unsigned h2u(v2h h){ union{v2h h; unsigned u;} c; c.h = h; return c.u; }

// pure-VALU 8-lane sum via compiler-managed DPP (hazard nops inserted by backend)
template<int CTRL>
__device__ __forceinline__ float dppadd(float x){
  int y = __builtin_amdgcn_update_dpp(0, __float_as_int(x), CTRL, 0xF, 0xF, true);
  return x + __int_as_float(y);
}
__device__ __forceinline__ float hsum8(float s){
  s = dppadd<0xB1>(s);    // xor 1
  s = dppadd<0x4E>(s);    // xor 2
  s = dppadd<0x141>(s);   // row_half_mirror: cross-quad within 8-lane group
  return s;
}
__device__ __forceinline__ float edge_w(v2h v, v2h xrv, v2h att2, float negm8){
  v2h t = v + xrv;
  t = __builtin_elementwise_max(t, t * (_Float16)NEGS);
  float s = hsum8(__builtin_amdgcn_fdot2(t, att2, negm8, false));
  return __builtin_amdgcn_exp2f(s);
}

// ---------------- input transform: h = relu(x @ w_in + b_in); also packed-f16 h16 ----------------
__global__ __launch_bounds__(256) void k_in(fp x, fp w, fp b, float* __restrict__ h,
                                            unsigned* __restrict__ h16, int N){
  __shared__ float ws[24*64];
  __shared__ float bs[64];
  __shared__ float xs[4][24];
  int tid = threadIdx.x;
  for (int i = tid; i < 24*64; i += 256) ws[i] = w[i];
  if (tid < 64) bs[tid] = b[tid];
  int r = tid >> 6, c = tid & 63;
  int row = blockIdx.x*4 + r;
  if (c < 24 && row < N) xs[r][c] = x[row*24 + c];
  __syncthreads();
  float acc = bs[c];
  #pragma unroll
  for (int k = 0; k < 24; ++k) acc = fmaf(xs[r][k], ws[k*64 + c], acc);
  float y = fmaxf(acc, 0.f);
  float y1 = __shfl_down(y, 1);
  if (row < N){
    h[(size_t)row*64 + c] = y;
    if (!(c & 1)){
      v2h p; p.x = (_Float16)y; p.y = (_Float16)y1;
      h16[(size_t)row*32 + (c >> 1)] = h2u(p);
    }
  }
}

// ---------------- weight prep: swizzle w_l/w_r into MFMA B-fragment layout (f16) ----------------
__global__ __launch_bounds__(256) void k_wprep(fp w_l, fp w_r, _Float16* __restrict__ wf){
  int lm = blockIdx.x;              // 0..5 : layer*2 + mat
  const float* src = ((lm & 1) ? w_r : w_l) + (lm >> 1)*4096;
  _Float16* dst = wf + lm*4096;
  for (int d = threadIdx.x; d < 4096; d += 256){
    int j = d & 7, l = (d >> 3) & 63, kc = (d >> 9) & 1, nt = d >> 10;
    int k = kc*32 + (l >> 4)*8 + j;
    int n = nt*16 + (l & 15);
    dst[d] = (_Float16)src[k*64 + n];
  }
}

// ---------------- CSR build: deterministic two-level counting sort ----------------
__global__ __launch_bounds__(256) void t_hist(const int* __restrict__ dstA, int* __restrict__ counts,
                                              int E, int K, int ntiles){
  __shared__ int hist[512];
  int t = blockIdx.x, tid = threadIdx.x;
  for (int i = tid; i < K; i += 256) hist[i] = 0;
  __syncthreads();
  int e0 = t*TILE, e1 = min(e0 + TILE, E);
  for (int e = e0 + tid; e < e1; e += 256)
    atomicAdd(&hist[dstA[e] >> BSH], 1);
  __syncthreads();
  for (int i = tid; i < K; i += 256) counts[i*ntiles + t] = hist[i];
}

__global__ __launch_bounds__(512) void s_scan_tiles(int* __restrict__ counts, int* __restrict__ btotal,
                                                    int ntiles){
  __shared__ int s[512];
  int b = blockIdx.x, tid = threadIdx.x;
  int v = (tid < ntiles) ? counts[b*ntiles + tid] : 0;
  s[tid] = v;
  __syncthreads();
  for (int off = 1; off < 512; off <<= 1){
    int t = (tid >= off) ? s[tid - off] : 0;
    __syncthreads();
    s[tid] += t;
    __syncthreads();
  }
  if (tid < ntiles) counts[b*ntiles + tid] = s[tid] - v;
  if (tid == 511) btotal[b] = s[511];
}

__global__ __launch_bounds__(512) void s_scan_buckets(const int* __restrict__ btotal,
                                                      int* __restrict__ bbase, int K, int E){
  __shared__ int s[512];
  int tid = threadIdx.x;
  int v = (tid < K) ? btotal[tid] : 0;
  s[tid] = v;
  __syncthreads();
  for (int off = 1; off < 512; off <<= 1){
    int t = (tid >= off) ? s[tid - off] : 0;
    __syncthreads();
    s[tid] += t;
    __syncthreads();
  }
  if (tid < K) bbase[tid] = s[tid] - v;
  if (tid == 0) bbase[K] = E;
}

__global__ __launch_bounds__(256) void t_scatter(const int* __restrict__ srcA, const int* __restrict__ dstA,
                                                 const int* __restrict__ counts, const int* __restrict__ bbase,
                                                 unsigned* __restrict__ packed, int E, int K, int ntiles){
  __shared__ int gb[512];
  __shared__ int cur[512];
  int t = blockIdx.x, tid = threadIdx.x;
  for (int i = tid; i < K; i += 256){
    gb[i] = bbase[i] + counts[i*ntiles + t];
    cur[i] = 0;
  }
  __syncthreads();
  int e0 = t*TILE, e1 = min(e0 + TILE, E);
  for (int e = e0 + tid; e < e1; e += 256){
    int d = dstA[e], sv = srcA[e];
    int b = d >> BSH;
    int p = atomicAdd(&cur[b], 1);
    packed[gb[b] + p] = ((unsigned)(d & (BN-1)) << 25) | (unsigned)sv;
  }
}

__global__ __launch_bounds__(256) void k_fine(const unsigned* __restrict__ packed, const int* __restrict__ bbase,
                                              int* __restrict__ row_ptr, int* __restrict__ col, int N, int K){
  __shared__ int hist[BN];
  __shared__ int excl[BN];
  int b = blockIdx.x, tid = threadIdx.x;
  int node0 = b << BSH;
  int e_base = bbase[b], e_end = bbase[b+1];
  if (tid < BN) hist[tid] = 0;
  __syncthreads();
  for (int e = e_base + tid; e < e_end; e += 256)
    atomicAdd(&hist[packed[e] >> 25], 1);
  __syncthreads();
  int v = (tid < BN) ? hist[tid] : 0;
  if (tid < BN) excl[tid] = v;
  __syncthreads();
  for (int off = 1; off < BN; off <<= 1){
    int t2 = 0;
    if (tid < BN && tid >= off) t2 = excl[tid - off];
    __syncthreads();
    if (tid < BN) excl[tid] += t2;
    __syncthreads();
  }
  int nn = min(BN, N - node0);
  if (tid < nn) row_ptr[node0 + tid] = e_base + excl[tid] - v;
  if (b == K-1 && tid == 0) row_ptr[N] = e_end;
  if (tid < BN) hist[tid] = excl[tid] - v;
  __syncthreads();
  for (int e = e_base + tid; e < e_end; e += 256){
    unsigned u = packed[e];
    int dl = u >> 25;
    int p = atomicAdd(&hist[dl], 1);
    col[e_base + p] = (int)(u & 0x1FFFFFFu);
  }
}

// ---------------- per-layer transforms via MFMA: xl16/xr16 = f16(h @ w + b) ----------------
__global__ __launch_bounds__(256) void k_xfm(const unsigned* __restrict__ h16,
                                             const _Float16* __restrict__ wf,   // layer base
                                             fp blg, fp brg,
                                             unsigned* __restrict__ xl16, unsigned* __restrict__ xr16, int N){
  int tid = threadIdx.x, wave = tid >> 6, lane = tid & 63;
  int quad = lane >> 4, ln = lane & 15;
  int m0 = blockIdx.x*64 + wave*16;
  if (m0 >= N) return;
  int m = m0 + ln;
  bool mv = m < N;
  v8h a0 = {}, a1 = {};
  if (mv){
    a0 = *(const v8h*)&h16[(size_t)m*32 + quad*4];
    a1 = *(const v8h*)&h16[(size_t)m*32 + 16 + quad*4];
  }
  #pragma unroll
  for (int mat = 0; mat < 2; ++mat){
    const _Float16* wb = wf + mat*4096;
    fp bias = mat ? brg : blg;
    unsigned* dst = mat ? xr16 : xl16;
    #pragma unroll
    for (int nt = 0; nt < 4; ++nt){
      v8h b0 = *(const v8h*)&wb[nt*1024 + lane*8];
      v8h b1 = *(const v8h*)&wb[nt*1024 + 512 + lane*8];
      float bv = bias[nt*16 + ln];
      v4f acc = {bv, bv, bv, bv};
      acc = __builtin_amdgcn_mfma_f32_16x16x32_f16(a0, b0, acc, 0, 0, 0);
      acc = __builtin_amdgcn_mfma_f32_16x16x32_f16(a1, b1, acc, 0, 0, 0);
      #pragma unroll
      for (int r = 0; r < 4; ++r){
        float partner = __shfl_xor(acc[r], 1);
        int node = m0 + quad*4 + r;
        if (!(lane & 1) && node < N){
          v2h p; p.x = (_Float16)acc[r]; p.y = (_Float16)partner;
          dst[(size_t)node*32 + nt*8 + (ln >> 1)] = h2u(p);
        }
      }
    }
  }
}

// ---------------- fused GATv2 aggregation + residual + LayerNorm (+relu) ----------------
// xl/xr packed f16 (2 features/lane, 32 lanes/row). Wave processes 2 edges at once
// (lower/upper halves); 16-edge unroll = 8 independent gathers in flight.
__global__ __launch_bounds__(256) void k_gat(const unsigned* __restrict__ xl16, const unsigned* __restrict__ xr16,
                                             float* __restrict__ h, unsigned* __restrict__ h16,
                                             const int* __restrict__ row_ptr, const int* __restrict__ col,
                                             fp att, fp bg, fp lng, fp lnb, int N, int do_relu){
  int lane = threadIdx.x & 63;
  int node = blockIdx.x*4 + (threadIdx.x >> 6);
  if (node >= N) return;
  int l = lane & 31;
  bool lower = lane < 32;
  int off = lower ? 0 : 1;
  v2h att2; att2.x = (_Float16)(att[2*l] * LOG2E); att2.y = (_Float16)(att[2*l+1] * LOG2E);
  v2h xrv = u2h(xr16[(size_t)node*32 + l]);
  v2h xlv = u2h(xl16[(size_t)node*32 + l]);
  v2h ts = xlv + xrv;
  ts = __builtin_elementwise_max(ts, ts * (_Float16)NEGS);
  const float m = hsum8(__builtin_amdgcn_fdot2(ts, att2, 0.f, false));
  const float negm8 = m * -0.125f;
  float den0 = lower ? 1.f : 0.f, den1 = 0.f, den2 = 0.f, den3 = 0.f;
  float a0x = lower ? (float)xlv.x : 0.f, a0y = lower ? (float)xlv.y : 0.f;
  float a1x = 0.f, a1y = 0.f, a2x = 0.f, a2y = 0.f, a3x = 0.f, a3y = 0.f;
  int e = row_ptr[node], e1 = row_ptr[node+1];
  for (; e + 16 <= e1; e += 16){
    int j0 = col[e+off],    j1 = col[e+2+off],  j2 = col[e+4+off],  j3 = col[e+6+off];
    int j4 = col[e+8+off],  j5 = col[e+10+off], j6 = col[e+12+off], j7 = col[e+14+off];
    v2h v0 = u2h(xl16[(size_t)j0*32 + l]);
    v2h v1 = u2h(xl16[(size_t)j1*32 + l]);
    v2h v2 = u2h(xl16[(size_t)j2*32 + l]);
    v2h v3 = u2h(xl16[(size_t)j3*32 + l]);
    v2h v4 = u2h(xl16[(size_t)j4*32 + l]);
    v2h v5 = u2h(xl16[(size_t)j5*32 + l]);
    v2h v6 = u2h(xl16[(size_t)j6*32 + l]);
    v2h v7 = u2h(xl16[(size_t)j7*32 + l]);
    float w0 = edge_w(v0, xrv, att2, negm8);
    float w1 = edge_w(v1, xrv, att2, negm8);
    float w2 = edge_w(v2, xrv, att2, negm8);
    float w3 = edge_w(v3, xrv, att2, negm8);
    float w4 = edge_w(v4, xrv, att2, negm8);
    float w5 = edge_w(v5, xrv, att2, negm8);
    float w6 = edge_w(v6, xrv, att2, negm8);
    float w7 = edge_w(v7, xrv, att2, negm8);
    den0 += w0; a0x = fmaf(w0, (float)v0.x, a0x); a0y = fmaf(w0, (float)v0.y, a0y);
    den1 += w1; a1x = fmaf(w1, (float)v1.x, a1x); a1y = fmaf(w1, (float)v1.y, a1y);
    den2 += w2; a2x = fmaf(w2, (float)v2.x, a2x); a2y = fmaf(w2, (float)v2.y, a2y);
    den3 += w3; a3x = fmaf(w3, (float)v3.x, a3x); a3y = fmaf(w3, (float)v3.y, a3y);
    den0 += w4; a0x = fmaf(w4, (float)v4.x, a0x); a0y = fmaf(w4, (float)v4.y, a0y);
    den1 += w5; a1x = fmaf(w5, (float)v5.x, a1x); a1y = fmaf(w5, (float)v5.y, a1y);
    den2 += w6; a2x = fmaf(w6, (float)v6.x, a2x); a2y = fmaf(w6, (float)v6.y, a2y);
    den3 += w7; a3x = fmaf(w7, (float)v7.x, a3x); a3y = fmaf(w7, (float)v7.y, a3y);
  }
  for (; e + 8 <= e1; e += 8){
    int j0 = col[e+off], j1 = col[e+2+off], j2 = col[e+4+off], j3 = col[e+6+off];
    v2h v0 = u2h(xl16[(size_t)j0*32 + l]);
    v2h v1 = u2h(xl16[(size_t)j1*32 + l]);
    v2h v2 = u2h(xl16[(size_t)j2*32 + l]);
    v2h v3 = u2h(xl16[(size_t)j3*32 + l]);
    float w0 = edge_w(v0, xrv, att2, negm8);
    float w1 = edge_w(v1, xrv, att2, negm8);
    float w2 = edge_w(v2, xrv, att2, negm8);
    float w3 = edge_w(v3, xrv, att2, negm8);
    den0 += w0; a0x = fmaf(w0, (float)v0.x, a0x); a0y = fmaf(w0, (float)v0.y, a0y);
    den1 += w1; a1x = fmaf(w1, (float)v1.x, a1x); a1y = fmaf(w1, (float)v1.y, a1y);
    den2 += w2; a2x = fmaf(w2, (float)v2.x, a2x); a2y = fmaf(w2, (float)v2.y, a2y);
    den3 += w3; a3x = fmaf(w3, (float)v3.x, a3x); a3y = fmaf(w3, (float)v3.y, a3y);
  }
  for (; e + 2 <= e1; e += 2){
    int j0 = col[e+off];
    v2h v0 = u2h(xl16[(size_t)j0*32 + l]);
    float w0 = edge_w(v0, xrv, att2, negm8);
    den0 += w0; a0x = fmaf(w0, (float)v0.x, a0x); a0y = fmaf(w0, (float)v0.y, a0y);
  }
  if (e < e1){
    int j0 = col[e];
    v2h v0 = u2h(xl16[(size_t)j0*32 + l]);
    float w0 = edge_w(v0, xrv, att2, negm8);
    if (!lower) w0 = 0.f;
    den0 += w0; a0x = fmaf(w0, (float)v0.x, a0x); a0y = fmaf(w0, (float)v0.y, a0y);
  }
  float den = (den0 + den1) + (den2 + den3);
  float ax = (a0x + a1x) + (a2x + a3x);
  float ay = (a0y + a1y) + (a2y + a3y);
  den += __shfl_xor(den, 32);
  ax  += __shfl_xor(ax, 32);
  ay  += __shfl_xor(ay, 32);
  float inv = 1.f / den;
  float2 bg2 = *(const float2*)&bg[2*l];
  float2 h2  = *(const float2*)&h[(size_t)node*64 + 2*l];
  float ox = ax*inv + bg2.x + h2.x;
  float oy = ay*inv + bg2.y + h2.y;
  float sl = ox + oy;
  #pragma unroll
  for (int o = 1; o < 32; o <<= 1) sl += __shfl_xor(sl, o);
  float mean = sl * (1.f/64.f);
  float dx = ox - mean, dy = oy - mean;
  float vsl = dx*dx + dy*dy;
  #pragma unroll
  for (int o = 1; o < 32; o <<= 1) vsl += __shfl_xor(vsl, o);
  float rs = rsqrtf(vsl * (1.f/64.f) + LN_EPS);
  float2 lg2 = *(const float2*)&lng[2*l];
  float2 lb2 = *(const float2*)&lnb[2*l];
  float yx = dx*rs*lg2.x + lb2.x;
  float yy = dy*rs*lg2.y + lb2.y;
  if (do_relu){ yx = fmaxf(yx, 0.f); yy = fmaxf(yy, 0.f); }
  if (lower){
    float2 y2; y2.x = yx; y2.y = yy;
    *(float2*)&h[(size_t)node*64 + 2*l] = y2;
    v2h p; p.x = (_Float16)yx; p.y = (_Float16)yy;
    h16[(size_t)node*32 + l] = h2u(p);
  }
}

// ---------------- gate MLP ----------------
__global__ __launch_bounds__(256) void k_gate(const float* __restrict__ h, fp w1, fp b1, fp w2, fp b2,
                                              float* __restrict__ gate, int N){
  __shared__ float w1s[2048];
  __shared__ float hrow[16][64];
  int tid = threadIdx.x;
  for (int i = tid*4; i < 2048; i += 1024) *(float4*)&w1s[i] = *(const float4*)&w1[i];
  int base = blockIdx.x*16;
  int nrows = min(16, N - base);
  int lim = nrows*64;
  for (int i = tid*4; i < lim; i += 1024)
    *(float4*)&hrow[0][i] = *(const float4*)&h[(size_t)base*64 + i];
  __syncthreads();
  int wave = tid >> 6, lane = tid & 63;
  int j = lane & 31, half = lane >> 5;
  float b1v = b1[j], w2v = w2[j], b2v = b2[0];
  int k0 = half*32;
  #pragma unroll
  for (int it = 0; it < 4; ++it){
    int r = wave*4 + it;
    int node = base + r;
    if (node >= N) break;
    float s = 0.f;
    #pragma unroll 8
    for (int k = k0; k < k0 + 32; ++k) s = fmaf(hrow[r][k], w1s[k*32 + j], s);
    s += __shfl_xor(s, 32);
    float hid = fmaxf(s + b1v, 0.f);
    float contrib = (half == 0) ? hid * w2v : 0.f;
    #pragma unroll
    for (int o = 1; o < 64; o <<= 1) contrib += __shfl_xor(contrib, o);
    if (lane == 0) gate[node] = contrib + b2v;
  }
}

// ---------------- per-graph gate max + zero pool accumulators ----------------
__global__ __launch_bounds__(256) void k_gmax(const float* __restrict__ gate, const int* __restrict__ batch,
                                              float* __restrict__ gmax, float* __restrict__ gsum,
                                              float* __restrict__ embsum, int N){
  int g = blockIdx.x, tid = threadIdx.x;
  if (tid < 64) embsum[g*64 + tid] = 0.f;
  if (tid == 64) gsum[g] = 0.f;
  int lo = 0, hi = N;
  while (lo < hi){ int mid = (lo + hi) >> 1; if (batch[mid] < g) lo = mid + 1; else hi = mid; }
  int start = lo;
  hi = N;
  while (lo < hi){ int mid = (lo + hi) >> 1; if (batch[mid] < g + 1) lo = mid + 1; else hi = mid; }
  int end = lo;
  float m = -3.4e38f;
  for (int i = start + tid; i < end; i += 256) m = fmaxf(m, gate[i]);
  #pragma unroll
  for (int o = 1; o < 64; o <<= 1) m = fmaxf(m, __shfl_xor(m, o));
  __shared__ float ws[4];
  if ((tid & 63) == 0) ws[tid >> 6] = m;
  __syncthreads();
  if (tid == 0) gmax[g] = fmaxf(fmaxf(ws[0], ws[1]), fmaxf(ws[2], ws[3]));
}

// ---------------- pooling accumulate ----------------
__global__ __launch_bounds__(256) void k_emb(const float* __restrict__ h, const float* __restrict__ gate,
                                             const int* __restrict__ batch, const float* __restrict__ gmax,
                                             float* __restrict__ gsum, float* __restrict__ embsum, int N){
  int lane = threadIdx.x & 63;
  int wv = blockIdx.x*4 + (threadIdx.x >> 6);
  int s = wv*64;
  if (s >= N) return;
  int e = min(s + 64, N);
  int cur = batch[s];
  float gm = gmax[cur];
  float acc = 0.f, asum = 0.f;
  for (int i = s; i < e; ++i){
    int g = batch[i];
    if (g != cur){
      atomicAdd(&embsum[cur*64 + lane], acc);
      if (lane == 0) atomicAdd(&gsum[cur], asum);
      acc = 0.f; asum = 0.f; cur = g; gm = gmax[g];
    }
    float a = __expf(gate[i] - gm);
    acc = fmaf(a, h[(size_t)i*64 + lane], acc);
    asum += a;
  }
  atomicAdd(&embsum[cur*64 + lane], acc);
  if (lane == 0) atomicAdd(&gsum[cur], asum);
}

// ---------------- final GEMM ----------------
__global__ __launch_bounds__(64) void k_out(const float* __restrict__ embsum, const float* __restrict__ gsum,
                                            fp w_out, fp b_out, float* __restrict__ out, int G){
  int g = blockIdx.x, lane = threadIdx.x;
  __shared__ float emb[64];
  float gs = gsum[g];
  float inv = (gs > 0.f) ? 1.f/gs : 1.f;
  emb[lane] = embsum[g*64 + lane] * inv;
  __syncthreads();
  float o2 = b_out[lane];
  #pragma unroll 8
  for (int d = 0; d < 64; ++d) o2 = fmaf(emb[d], w_out[d*64 + lane], o2);
  out[g*64 + lane] = fmaxf(o2, 0.f);
}

extern "C" void kernel_launch(void* const* d_in, const int* in_sizes, int n_in,
                              void* d_out, int out_size, void* d_ws, size_t ws_size,
                              hipStream_t stream) {
  const int N = in_sizes[0] / 24;
  const int E = in_sizes[1] / 2;
  const int G = out_size / 64;
  const int K = (N + BN - 1) >> BSH;
  const int ntiles = (E + TILE - 1) / TILE;

  fp x      = (fp)d_in[0];
  const int* edge  = (const int*)d_in[1];
  const int* batch = (const int*)d_in[2];
  fp w_in   = (fp)d_in[3];
  fp b_in   = (fp)d_in[4];
  fp w_l    = (fp)d_in[5];
  fp b_l    = (fp)d_in[6];
  fp w_r    = (fp)d_in[7];
  fp b_r    = (fp)d_in[8];
  fp att    = (fp)d_in[9];
  fp b_gat  = (fp)d_in[10];
  fp ln_g   = (fp)d_in[11];
  fp ln_b   = (fp)d_in[12];
  fp w_g1   = (fp)d_in[13];
  fp b_g1   = (fp)d_in[14];
  fp w_g2   = (fp)d_in[15];
  fp b_g2   = (fp)d_in[16];
  fp w_out  = (fp)d_in[17];
  fp b_out  = (fp)d_in[18];
  float* out = (float*)d_out;

  char* wp = (char*)d_ws;
  auto alloc = [&](size_t bytes) -> char* {
    char* p = wp; wp += (bytes + 255) & ~(size_t)255; return p;
  };
  float*    h       = (float*)    alloc((size_t)N*64*sizeof(float));
  unsigned* h16     = (unsigned*) alloc((size_t)N*32*sizeof(unsigned));
  unsigned* xl16    = (unsigned*) alloc((size_t)N*32*sizeof(unsigned));
  unsigned* xr16    = (unsigned*) alloc((size_t)N*32*sizeof(unsigned));
  int*      col     = (int*)      alloc((size_t)E*sizeof(int));
  unsigned* packed  = (unsigned*) alloc((size_t)E*sizeof(unsigned));
  int*      counts  = (int*)      alloc((size_t)K*ntiles*sizeof(int));
  int*      btotal  = (int*)      alloc((size_t)K*sizeof(int));
  int*      bbase   = (int*)      alloc((size_t)(K+1)*sizeof(int));
  int*      row_ptr = (int*)      alloc((size_t)(N+1)*sizeof(int));
  float*    gate    = (float*)    alloc((size_t)N*sizeof(float));
  float*    gmax    = (float*)    alloc((size_t)G*sizeof(float));
  float*    gsum    = (float*)    alloc((size_t)(G + G*64)*sizeof(float));
  float*    embsum  = gsum + G;
  _Float16* wf      = (_Float16*) alloc((size_t)3*2*4096*sizeof(_Float16));

  const int* srcA = edge;
  const int* dstA = edge + E;

  k_in<<<(N + 3)/4, 256, 0, stream>>>(x, w_in, b_in, h, h16, N);
  k_wprep<<<6, 256, 0, stream>>>(w_l, w_r, wf);

  t_hist<<<ntiles, 256, 0, stream>>>(dstA, counts, E, K, ntiles);
  s_scan_tiles<<<K, 512, 0, stream>>>(counts, btotal, ntiles);
  s_scan_buckets<<<1, 512, 0, stream>>>(btotal, bbase, K, E);
  t_scatter<<<ntiles, 256, 0, stream>>>(srcA, dstA, counts, bbase, packed, E, K, ntiles);
  k_fine<<<K, 256, 0, stream>>>(packed, bbase, row_ptr, col, N, K);

  for (int i = 0; i < 3; ++i){
    k_xfm<<<(N + 63)/64, 256, 0, stream>>>(h16, wf + i*8192, b_l + i*64, b_r + i*64,
                                           xl16, xr16, N);
    k_gat<<<(N + 3)/4, 256, 0, stream>>>(xl16, xr16, h, h16, row_ptr, col,
                                         att + i*64, b_gat + i*64, ln_g + i*64, ln_b + i*64,
                                         N, i < 2 ? 1 : 0);
  }
  k_gate<<<(N + 15)/16, 256, 0, stream>>>(h, w_g1, b_g1, w_g2, b_g2, gate, N);
  k_gmax<<<G, 256, 0, stream>>>(gate, batch, gmax, gsum, embsum, N);
  k_emb<<<(N + 255)/256, 256, 0, stream>>>(h, gate, batch, gmax, gsum, embsum, N);
  k_out<<<G, 64, 0, stream>>>(embsum, gsum, w_out, b_out, out, G);
}